// Round 4
// baseline (528.379 us; speedup 1.0000x reference)
//
#include <hip/hip_runtime.h>
#include <hip/hip_bf16.h>

#define NN 100000      // N_SRC == N_DST
#define EDGES 500000
#define DD 128
#define NBKT 196       // buckets of 512 nodes (100000/512 -> 196)
#define SLACK 3584     // per-bucket record capacity (mean 2551, sigma ~50 -> 20 sigma margin)
#define CHUNK 4096     // edges per bin_scatter block
#define BPD ((EDGES + CHUNK - 1) / CHUNK)   // 123

typedef short bf16x8 __attribute__((ext_vector_type(8)));
typedef float f32x4  __attribute__((ext_vector_type(4)));

__device__ __forceinline__ unsigned short f2bf(float f) {
    unsigned u = __float_as_uint(f);
    u += 0x7fffu + ((u >> 16) & 1u);      // round-to-nearest-even (no NaN inputs here)
    return (unsigned short)(u >> 16);
}

// ---------------- fp32 -> bf16 conversions (fused launches) ----------------
__global__ void f2bx_kernel(const float* __restrict__ a, const float* __restrict__ b,
                            unsigned short* __restrict__ oa, unsigned short* __restrict__ ob) {
    const float* in = blockIdx.y ? b : a;
    unsigned short* out = blockIdx.y ? ob : oa;
    int i = blockIdx.x * 256 + threadIdx.x;          // i < NN*DD/4
    float4 v = ((const float4*)in)[i];
    ushort4 o;
    o.x = f2bf(v.x); o.y = f2bf(v.y); o.z = f2bf(v.z); o.w = f2bf(v.w);
    ((ushort4*)out)[i] = o;
}

__global__ void f2bw_kernel(const float* __restrict__ w0, const float* __restrict__ w1,
                            const float* __restrict__ w2, const float* __restrict__ w3,
                            unsigned short* __restrict__ o0, unsigned short* __restrict__ o1,
                            unsigned short* __restrict__ o2, unsigned short* __restrict__ o3) {
    const float* in; unsigned short* out;
    switch (blockIdx.y) {
        case 0: in = w0; out = o0; break;
        case 1: in = w1; out = o1; break;
        case 2: in = w2; out = o2; break;
        default: in = w3; out = o3; break;
    }
    int i = blockIdx.x * 256 + threadIdx.x;          // i < 2*DD*DD/4 = 8192
    float4 v = ((const float4*)in)[i];
    ushort4 o;
    o.x = f2bf(v.x); o.y = f2bf(v.y); o.z = f2bf(v.z); o.w = f2bf(v.w);
    ((ushort4*)out)[i] = o;
}

// ---------------- pass 1: bucket-binned edge scatter (LDS multisplit) ----------------
__global__ __launch_bounds__(256) void bin_scatter_kernel(
    const int* __restrict__ e_src, const int* __restrict__ e_dst,
    int* __restrict__ gcnt,              // [2*256], zero-initialized
    unsigned* __restrict__ recbin)       // [2 * NBKT * SLACK]
{
    const int dir = blockIdx.y;
    const int t = threadIdx.x;
    const int c0 = blockIdx.x * CHUNK;
    const int nvalid = min(CHUNK, EDGES - c0);
    const int* __restrict__ TGT = dir ? e_src : e_dst;
    const int* __restrict__ PAY = dir ? e_dst : e_src;

    __shared__ int hist[256];
    __shared__ int lbase[256];
    __shared__ int lofs[256];
    __shared__ int scanA[256], scanB[256];
    __shared__ int laddr[CHUNK];
    __shared__ unsigned lrec[CHUNK];

    hist[t] = 0;
    __syncthreads();

    int myb[16], myslot[16];
    unsigned myrec[16];
    #pragma unroll
    for (int j = 0; j < 16; ++j) {
        int e = c0 + j * 256 + t;
        myb[j] = -1;
        if (e < EDGES) {
            int tgt = TGT[e], pay = PAY[e];
            int b = tgt >> 9;
            myb[j] = b;
            myrec[j] = ((unsigned)pay << 9) | (unsigned)(tgt & 511);
            myslot[j] = atomicAdd(&hist[b], 1);
        }
    }
    __syncthreads();
    int cnt = hist[t];
    lbase[t] = (cnt > 0) ? atomicAdd(&gcnt[dir * 256 + t], cnt) : 0;
    scanA[t] = cnt;
    __syncthreads();
    int* pa = scanA; int* pb = scanB;
    for (int d = 1; d < 256; d <<= 1) {
        pb[t] = pa[t] + (t >= d ? pa[t - d] : 0);
        __syncthreads();
        int* tmp = pa; pa = pb; pb = tmp;
    }
    lofs[t] = pa[t] - cnt;                 // exclusive scan
    __syncthreads();
    #pragma unroll
    for (int j = 0; j < 16; ++j) {
        if (myb[j] >= 0) {
            int b = myb[j];
            int pos = lofs[b] + myslot[j];
            int g = lbase[b] + myslot[j];
            lrec[pos] = myrec[j];
            laddr[pos] = (g < SLACK) ? (b * SLACK + g) : -1;   // overflow guard (won't trigger)
        }
    }
    __syncthreads();
    unsigned* __restrict__ out = recbin + (size_t)dir * NBKT * SLACK;
    #pragma unroll
    for (int j = 0; j < 16; ++j) {
        int i = j * 256 + t;
        if (i < nvalid) {
            int a = laddr[i];
            if (a >= 0) out[a] = lrec[i];  // bucket-sorted -> near-coalesced runs
        }
    }
}

// ---------------- pass 2: tiny scan of bucket counts -> csr bases ----------------
__global__ void bucket_scan_kernel(const int* __restrict__ gcnt, int* __restrict__ csr_base) {
    int t = threadIdx.x;
    __shared__ int A[256], B[256];
    for (int dir = 0; dir < 2; ++dir) {
        int c = (t < NBKT) ? min(gcnt[dir * 256 + t], SLACK) : 0;
        A[t] = c;
        __syncthreads();
        int* pa = A; int* pb = B;
        for (int d = 1; d < 256; d <<= 1) {
            pb[t] = pa[t] + (t >= d ? pa[t - d] : 0);
            __syncthreads();
            int* tmp = pa; pa = pb; pb = tmp;
        }
        if (t < NBKT) csr_base[dir * 200 + t] = pa[t] - c;
        if (t == 0)   csr_base[dir * 200 + NBKT] = pa[255];   // total (== EDGES)
        __syncthreads();
    }
}

// ---------------- pass 3: per-bucket fine placement + rp + invdeg ----------------
__global__ __launch_bounds__(256) void fine_place_kernel(
    const unsigned* __restrict__ recbin, const int* __restrict__ gcnt,
    const int* __restrict__ csr_base,
    int* __restrict__ rp_dst, int* __restrict__ rp_src,
    float* __restrict__ inv_dst, float* __restrict__ inv_src,
    int* __restrict__ csr_dst, int* __restrict__ csr_src)
{
    const int dir = blockIdx.y;
    const int bkt = blockIdx.x;
    const int t = threadIdx.x;
    int*   __restrict__ rp  = dir ? rp_src  : rp_dst;
    float* __restrict__ inv = dir ? inv_src : inv_dst;
    int*   __restrict__ csr = dir ? csr_src : csr_dst;
    const unsigned* __restrict__ recs = recbin + ((size_t)dir * NBKT + bkt) * SLACK;
    const int cnt = min(gcnt[dir * 256 + bkt], SLACK);
    const int cbase = csr_base[dir * 200 + bkt];
    const int n0 = bkt * 512;

    __shared__ int deg[512];
    __shared__ int sA[512], sB[512];
    __shared__ int cur[512];
    deg[t] = 0; deg[t + 256] = 0;
    __syncthreads();
    for (int i = t; i < cnt; i += 256)
        atomicAdd(&deg[recs[i] & 511u], 1);
    __syncthreads();
    sA[t] = deg[t]; sA[t + 256] = deg[t + 256];
    __syncthreads();
    int* pa = sA; int* pb = sB;
    for (int d = 1; d < 512; d <<= 1) {
        pb[t]       = pa[t]       + (t >= d           ? pa[t - d]       : 0);
        pb[t + 256] = pa[t + 256] + ((t + 256) >= d   ? pa[t + 256 - d] : 0);
        __syncthreads();
        int* tmp = pa; pa = pb; pb = tmp;
    }
    #pragma unroll
    for (int k = 0; k < 2; ++k) {
        int i = t + k * 256;
        int off = pa[i] - deg[i];          // exclusive
        cur[i] = off;
        int node = n0 + i;
        if (node < NN) {
            rp[node] = cbase + off;        // coalesced rp write
            inv[node] = 1.0f / (float)max(deg[i], 1);
        }
    }
    if (bkt == NBKT - 1 && t == 0) rp[NN] = csr_base[dir * 200 + NBKT];
    __syncthreads();
    for (int i = t; i < cnt; i += 256) {
        unsigned r = recs[i];
        int p = atomicAdd(&cur[r & 511u], 1);
        csr[cbase + p] = (int)(r >> 9);    // scattered 4B stores within ~10KB window
    }
}

// ---------------- mean aggregation (bf16, fused both directions) ----------------
__global__ void aggregate2_kernel(
    const unsigned short* __restrict__ h0, const int* __restrict__ rp0,
    const int* __restrict__ csr0, const float* __restrict__ inv0, unsigned short* __restrict__ ag0,
    const unsigned short* __restrict__ h1, const int* __restrict__ rp1,
    const int* __restrict__ csr1, const float* __restrict__ inv1, unsigned short* __restrict__ ag1)
{
    const int dir = blockIdx.y;
    const unsigned short* __restrict__ h = dir ? h1 : h0;
    const int* __restrict__ rp   = dir ? rp1 : rp0;
    const int* __restrict__ csr  = dir ? csr1 : csr0;
    const float* __restrict__ inv = dir ? inv1 : inv0;
    unsigned short* __restrict__ agg = dir ? ag1 : ag0;

    int wid  = (int)((blockIdx.x * 256u + threadIdx.x) >> 6);
    int lane = threadIdx.x & 63;
    if (wid >= NN) return;
    int beg = rp[wid], end = rp[wid + 1];
    float a0 = 0.f, a1 = 0.f, b0 = 0.f, b1 = 0.f;
    int i = beg;
    for (; i + 1 < end; i += 2) {          // unroll-2: two independent gather chains
        int c0 = csr[i], c1 = csr[i + 1];
        unsigned v0 = *(const unsigned*)(h + (size_t)c0 * DD + lane * 2);
        unsigned v1 = *(const unsigned*)(h + (size_t)c1 * DD + lane * 2);
        a0 += __uint_as_float(v0 << 16); a1 += __uint_as_float(v0 & 0xffff0000u);
        b0 += __uint_as_float(v1 << 16); b1 += __uint_as_float(v1 & 0xffff0000u);
    }
    if (i < end) {
        unsigned v = *(const unsigned*)(h + (size_t)csr[i] * DD + lane * 2);
        a0 += __uint_as_float(v << 16); a1 += __uint_as_float(v & 0xffff0000u);
    }
    float sc = inv[wid];
    a0 = (a0 + b0) * sc; a1 = (a1 + b1) * sc;
    unsigned o = (unsigned)f2bf(a0) | ((unsigned)f2bf(a1) << 16);
    *(unsigned*)(agg + (size_t)wid * DD + lane * 2) = o;
}

// ---------------- MFMA GEMM (fused both directions), barrier-free K-loop ----------------
// out = relu([Hself|Hagg] @ [Wself|Wneigh]^T + b), bf16 in, fp32 acc.
// 128x128 block, 4 waves, each 64x64 (4x4 MFMA 16x16x32 tiles), fused K=256.
// Weights staged once in LDS (64 KB, swizzled) -> ONE __syncthreads per block.
// A-fragments load global->VGPR directly: 16B/lane over 16 rows = 16 fully-used
// 64B lines per instr; 1-deep register double-buffer (a_nxt/b_nxt) hides latency
// with fine-grained vmcnt (no vmcnt(0) barrier drains).
// In-place safe: block reads only its own rows; all A reads precede epilogue stores.
__global__ __launch_bounds__(256, 2) void mfma_gemm2_kernel(
    const unsigned short* __restrict__ Hs0, const unsigned short* __restrict__ Ha0,
    const unsigned short* __restrict__ Ws0, const unsigned short* __restrict__ Wn0,
    const float* __restrict__ bias0, float* __restrict__ outF0, unsigned short* __restrict__ outB0,
    const unsigned short* __restrict__ Hs1, const unsigned short* __restrict__ Ha1,
    const unsigned short* __restrict__ Ws1, const unsigned short* __restrict__ Wn1,
    const float* __restrict__ bias1, float* __restrict__ outF1, unsigned short* __restrict__ outB1,
    int M)
{
    const int dir = blockIdx.y;
    const unsigned short* __restrict__ Hself = dir ? Hs1 : Hs0;
    const unsigned short* __restrict__ Hagg  = dir ? Ha1 : Ha0;
    const unsigned short* __restrict__ Wself = dir ? Ws1 : Ws0;
    const unsigned short* __restrict__ Wneigh= dir ? Wn1 : Wn0;
    const float* __restrict__ bias = dir ? bias1 : bias0;
    float* __restrict__ outF = dir ? outF1 : outF0;
    unsigned short* __restrict__ outB = dir ? outB1 : outB0;

    __shared__ __align__(16) unsigned short sW[128 * 256];  // fused weights, swizzled (64 KB)
    const int tid  = threadIdx.x;
    const int lane = tid & 63;
    const int w    = tid >> 6;
    const int row0 = blockIdx.x * 128;

    #pragma unroll
    for (int i = 0; i < 16; ++i) {       // stage fused weights (swizzled)
        int q = i * 256 + tid;
        int n = q >> 5, c = q & 31;
        const unsigned short* src = (c < 16) ? (Wself + n * 128 + c * 8)
                                             : (Wneigh + n * 128 + (c - 16) * 8);
        int d = n * 256 + (c & 24) * 8 + (((c ^ n) & 7) * 8);
        *(uint4*)(sW + d) = *(const uint4*)src;
    }

    f32x4 acc[4][4];
    #pragma unroll
    for (int mt = 0; mt < 4; ++mt)
        #pragma unroll
        for (int nt = 0; nt < 4; ++nt) acc[mt][nt] = (f32x4){0.f, 0.f, 0.f, 0.f};

    const int mbase = (w >> 1) * 64;
    const int nbase = (w & 1) * 64;
    const int l15 = lane & 15;
    const int l4  = lane >> 4;

    // per-mt A row pointers (row-clamped); lane offset l4*8 shorts baked in
    const unsigned short* aps[4];
    const unsigned short* apa[4];
    #pragma unroll
    for (int mt = 0; mt < 4; ++mt) {
        int grow = row0 + mbase + mt * 16 + l15;
        if (grow >= M) grow = M - 1;
        aps[mt] = Hself + (size_t)grow * 128 + l4 * 8;
        apa[mt] = Hagg  + (size_t)grow * 128 + l4 * 8;
    }

    __syncthreads();   // the ONLY barrier: weights ready

    bf16x8 a_cur[4], a_nxt[4], b_cur[4], b_nxt[4];
    #pragma unroll
    for (int mt = 0; mt < 4; ++mt) a_cur[mt] = *(const bf16x8*)(aps[mt]);
    #pragma unroll
    for (int nt = 0; nt < 4; ++nt) {
        int n = nbase + nt * 16 + l15;
        b_cur[nt] = *(const bf16x8*)(sW + n * 256 + (((l4 ^ n) & 7) * 8));
    }

    #pragma unroll
    for (int ks = 0; ks < 8; ++ks) {
        if (ks < 7) {
            const int ks1 = ks + 1;
            const int col = (ks1 & 3) * 32;     // shorts
            #pragma unroll
            for (int mt = 0; mt < 4; ++mt)
                a_nxt[mt] = *(const bf16x8*)(((ks1 < 4) ? aps[mt] : apa[mt]) + col);
            const int c1 = ks1 * 4 + l4;
            #pragma unroll
            for (int nt = 0; nt < 4; ++nt) {
                int n = nbase + nt * 16 + l15;
                b_nxt[nt] = *(const bf16x8*)(sW + n * 256 + (c1 & 24) * 8 + (((c1 ^ n) & 7) * 8));
            }
        }
        #pragma unroll
        for (int mt = 0; mt < 4; ++mt)
            #pragma unroll
            for (int nt = 0; nt < 4; ++nt)
                acc[mt][nt] = __builtin_amdgcn_mfma_f32_16x16x32_bf16(a_cur[mt], b_cur[nt], acc[mt][nt], 0, 0, 0);
        #pragma unroll
        for (int mt = 0; mt < 4; ++mt) a_cur[mt] = a_nxt[mt];
        #pragma unroll
        for (int nt = 0; nt < 4; ++nt) b_cur[nt] = b_nxt[nt];
    }

    #pragma unroll
    for (int nt = 0; nt < 4; ++nt) {
        int col = nbase + nt * 16 + l15;
        float bj = bias[col];
        #pragma unroll
        for (int mt = 0; mt < 4; ++mt) {
            #pragma unroll
            for (int r = 0; r < 4; ++r) {
                int grow = row0 + mbase + mt * 16 + l4 * 4 + r;
                if (grow < M) {
                    float v = fmaxf(acc[mt][nt][r] + bj, 0.f);
                    if (outF) outF[(size_t)grow * 128 + col] = v;
                    else      outB[(size_t)grow * 128 + col] = f2bf(v);
                }
            }
        }
    }
}

extern "C" void kernel_launch(void* const* d_in, const int* in_sizes, int n_in,
                              void* d_out, int out_size, void* d_ws, size_t ws_size,
                              hipStream_t stream) {
    const float* x_src        = (const float*)d_in[0];
    const float* x_dst        = (const float*)d_in[1];
    const int*   e_src        = (const int*)d_in[2];
    const int*   e_dst        = (const int*)d_in[3];
    const float* W_ship_self  = (const float*)d_in[4];
    const float* W_ship_neigh = (const float*)d_in[5];
    const float* b_ship       = (const float*)d_in[6];
    const float* W_rev_self   = (const float*)d_in[7];
    const float* W_rev_neigh  = (const float*)d_in[8];
    const float* b_rev        = (const float*)d_in[9];
    float* out = (float*)d_out;

    char* ws = (char*)d_ws;
    size_t off = 0;
    auto alloc = [&](size_t bytes) {
        char* p = ws + off;
        off = (off + bytes + 255) & ~(size_t)255;
        return p;
    };
    unsigned short* xs_bf = (unsigned short*)alloc((size_t)NN * DD * 2);
    unsigned short* xd_bf = (unsigned short*)alloc((size_t)NN * DD * 2);
    unsigned short* agg1  = (unsigned short*)alloc((size_t)NN * DD * 2);
    unsigned short* agg2  = (unsigned short*)alloc((size_t)NN * DD * 2);
    unsigned short* Wss_bf = (unsigned short*)alloc(2 * DD * DD * 2);
    unsigned short* Wsn_bf = (unsigned short*)alloc(2 * DD * DD * 2);
    unsigned short* Wrs_bf = (unsigned short*)alloc(2 * DD * DD * 2);
    unsigned short* Wrn_bf = (unsigned short*)alloc(2 * DD * DD * 2);
    int* gcnt = (int*)alloc(2 * 256 * 4);
    int* csr_base = (int*)alloc(2 * 200 * 4);
    unsigned* recbin = (unsigned*)alloc((size_t)2 * NBKT * SLACK * 4);
    int* rp_dst = (int*)alloc((NN + 1) * 4);
    int* rp_src = (int*)alloc((NN + 1) * 4);
    float* inv_dst = (float*)alloc(NN * 4);
    float* inv_src = (float*)alloc(NN * 4);
    int* csr_dst = (int*)alloc(EDGES * 4);
    int* csr_src = (int*)alloc(EDGES * 4);
    (void)ws_size; (void)in_sizes; (void)n_in; (void)out_size;

    hipMemsetAsync(gcnt, 0, 2 * 256 * 4, stream);

    const int xn4 = NN * DD / 4;                       // 3,200,000
    f2bx_kernel<<<dim3(xn4 / 256, 2), 256, 0, stream>>>(x_src, x_dst, xs_bf, xd_bf);
    f2bw_kernel<<<dim3(32, 4), 256, 0, stream>>>(W_ship_self, W_ship_neigh, W_rev_self, W_rev_neigh,
                                                 Wss_bf, Wsn_bf, Wrs_bf, Wrn_bf);

    bin_scatter_kernel<<<dim3(BPD, 2), 256, 0, stream>>>(e_src, e_dst, gcnt, recbin);
    bucket_scan_kernel<<<1, 256, 0, stream>>>(gcnt, csr_base);
    fine_place_kernel<<<dim3(NBKT, 2), 256, 0, stream>>>(recbin, gcnt, csr_base,
        rp_dst, rp_src, inv_dst, inv_src, csr_dst, csr_src);

    float* out_s = out;                       // h_s final
    float* out_d = out + (size_t)NN * DD;     // h_d final
    const int gemm_grid = (NN + 127) / 128;   // 782
    const int agg_grid  = (NN * 64 + 255) / 256;  // 25000

    for (int l = 0; l < 2; ++l) {
        // dir0: agg1 = mean h_s by dst ; dir1: agg2 = mean h_d by src
        aggregate2_kernel<<<dim3(agg_grid, 2), 256, 0, stream>>>(
            xs_bf, rp_dst, csr_dst, inv_dst, agg1,
            xd_bf, rp_src, csr_src, inv_src, agg2);
        // dir0: new_d = relu(h_d@Wss^T + agg1@Wsn^T + b_ship)
        // dir1: new_s = relu(h_s@Wrs^T + agg2@Wrn^T + b_rev)
        mfma_gemm2_kernel<<<dim3(gemm_grid, 2), 256, 0, stream>>>(
            xd_bf, agg1, Wss_bf + l * DD * DD, Wsn_bf + l * DD * DD, b_ship + l * DD,
            l ? out_d : nullptr, l ? nullptr : xd_bf,
            xs_bf, agg2, Wrs_bf + l * DD * DD, Wrn_bf + l * DD * DD, b_rev + l * DD,
            l ? out_s : nullptr, l ? nullptr : xs_bf,
            NN);
    }
}

// Round 5
// 485.135 us; speedup vs baseline: 1.0891x; 1.0891x over previous
//
#include <hip/hip_runtime.h>
#include <hip/hip_bf16.h>

#define NN 100000      // N_SRC == N_DST
#define EDGES 500000
#define DD 128
#define NBKT 196       // buckets of 512 nodes (100000/512 -> 196)
#define SLACK 3584     // per-bucket record capacity (mean 2551, sigma ~50 -> 20 sigma margin)
#define CHUNK 4096     // edges per bin_scatter block
#define BPD ((EDGES + CHUNK - 1) / CHUNK)   // 123

typedef short bf16x8 __attribute__((ext_vector_type(8)));
typedef float f32x4  __attribute__((ext_vector_type(4)));

__device__ __forceinline__ unsigned short f2bf(float f) {
    unsigned u = __float_as_uint(f);
    u += 0x7fffu + ((u >> 16) & 1u);      // round-to-nearest-even (no NaN inputs here)
    return (unsigned short)(u >> 16);
}

// ---------------- fp32 -> bf16 conversions (fused launches) ----------------
__global__ void f2bx_kernel(const float* __restrict__ a, const float* __restrict__ b,
                            unsigned short* __restrict__ oa, unsigned short* __restrict__ ob) {
    const float* in = blockIdx.y ? b : a;
    unsigned short* out = blockIdx.y ? ob : oa;
    int i = blockIdx.x * 256 + threadIdx.x;          // i < NN*DD/4
    float4 v = ((const float4*)in)[i];
    ushort4 o;
    o.x = f2bf(v.x); o.y = f2bf(v.y); o.z = f2bf(v.z); o.w = f2bf(v.w);
    ((ushort4*)out)[i] = o;
}

__global__ void f2bw_kernel(const float* __restrict__ w0, const float* __restrict__ w1,
                            const float* __restrict__ w2, const float* __restrict__ w3,
                            unsigned short* __restrict__ o0, unsigned short* __restrict__ o1,
                            unsigned short* __restrict__ o2, unsigned short* __restrict__ o3) {
    const float* in; unsigned short* out;
    switch (blockIdx.y) {
        case 0: in = w0; out = o0; break;
        case 1: in = w1; out = o1; break;
        case 2: in = w2; out = o2; break;
        default: in = w3; out = o3; break;
    }
    int i = blockIdx.x * 256 + threadIdx.x;          // i < 2*DD*DD/4 = 8192
    float4 v = ((const float4*)in)[i];
    ushort4 o;
    o.x = f2bf(v.x); o.y = f2bf(v.y); o.z = f2bf(v.z); o.w = f2bf(v.w);
    ((ushort4*)out)[i] = o;
}

// ---------------- pass 1: bucket-binned edge scatter (LDS multisplit) ----------------
__global__ __launch_bounds__(256) void bin_scatter_kernel(
    const int* __restrict__ e_src, const int* __restrict__ e_dst,
    int* __restrict__ gcnt,              // [2*256], zero-initialized
    unsigned* __restrict__ recbin)       // [2 * NBKT * SLACK]
{
    const int dir = blockIdx.y;
    const int t = threadIdx.x;
    const int c0 = blockIdx.x * CHUNK;
    const int nvalid = min(CHUNK, EDGES - c0);
    const int* __restrict__ TGT = dir ? e_src : e_dst;
    const int* __restrict__ PAY = dir ? e_dst : e_src;

    __shared__ int hist[256];
    __shared__ int lbase[256];
    __shared__ int lofs[256];
    __shared__ int scanA[256], scanB[256];
    __shared__ int laddr[CHUNK];
    __shared__ unsigned lrec[CHUNK];

    hist[t] = 0;
    __syncthreads();

    int myb[16], myslot[16];
    unsigned myrec[16];
    #pragma unroll
    for (int j = 0; j < 16; ++j) {
        int e = c0 + j * 256 + t;
        myb[j] = -1;
        if (e < EDGES) {
            int tgt = TGT[e], pay = PAY[e];
            int b = tgt >> 9;
            myb[j] = b;
            myrec[j] = ((unsigned)pay << 9) | (unsigned)(tgt & 511);
            myslot[j] = atomicAdd(&hist[b], 1);
        }
    }
    __syncthreads();
    int cnt = hist[t];
    lbase[t] = (cnt > 0) ? atomicAdd(&gcnt[dir * 256 + t], cnt) : 0;
    scanA[t] = cnt;
    __syncthreads();
    int* pa = scanA; int* pb = scanB;
    for (int d = 1; d < 256; d <<= 1) {
        pb[t] = pa[t] + (t >= d ? pa[t - d] : 0);
        __syncthreads();
        int* tmp = pa; pa = pb; pb = tmp;
    }
    lofs[t] = pa[t] - cnt;                 // exclusive scan
    __syncthreads();
    #pragma unroll
    for (int j = 0; j < 16; ++j) {
        if (myb[j] >= 0) {
            int b = myb[j];
            int pos = lofs[b] + myslot[j];
            int g = lbase[b] + myslot[j];
            lrec[pos] = myrec[j];
            laddr[pos] = (g < SLACK) ? (b * SLACK + g) : -1;   // overflow guard (won't trigger)
        }
    }
    __syncthreads();
    unsigned* __restrict__ out = recbin + (size_t)dir * NBKT * SLACK;
    #pragma unroll
    for (int j = 0; j < 16; ++j) {
        int i = j * 256 + t;
        if (i < nvalid) {
            int a = laddr[i];
            if (a >= 0) out[a] = lrec[i];  // bucket-sorted -> near-coalesced runs
        }
    }
}

// ---------------- pass 2: tiny scan of bucket counts -> csr bases ----------------
__global__ void bucket_scan_kernel(const int* __restrict__ gcnt, int* __restrict__ csr_base) {
    int t = threadIdx.x;
    __shared__ int A[256], B[256];
    for (int dir = 0; dir < 2; ++dir) {
        int c = (t < NBKT) ? min(gcnt[dir * 256 + t], SLACK) : 0;
        A[t] = c;
        __syncthreads();
        int* pa = A; int* pb = B;
        for (int d = 1; d < 256; d <<= 1) {
            pb[t] = pa[t] + (t >= d ? pa[t - d] : 0);
            __syncthreads();
            int* tmp = pa; pa = pb; pb = tmp;
        }
        if (t < NBKT) csr_base[dir * 200 + t] = pa[t] - c;
        if (t == 0)   csr_base[dir * 200 + NBKT] = pa[255];   // total (== EDGES)
        __syncthreads();
    }
}

// ---------------- pass 3: per-bucket fine placement + rp + invdeg ----------------
__global__ __launch_bounds__(256) void fine_place_kernel(
    const unsigned* __restrict__ recbin, const int* __restrict__ gcnt,
    const int* __restrict__ csr_base,
    int* __restrict__ rp_dst, int* __restrict__ rp_src,
    float* __restrict__ inv_dst, float* __restrict__ inv_src,
    int* __restrict__ csr_dst, int* __restrict__ csr_src)
{
    const int dir = blockIdx.y;
    const int bkt = blockIdx.x;
    const int t = threadIdx.x;
    int*   __restrict__ rp  = dir ? rp_src  : rp_dst;
    float* __restrict__ inv = dir ? inv_src : inv_dst;
    int*   __restrict__ csr = dir ? csr_src : csr_dst;
    const unsigned* __restrict__ recs = recbin + ((size_t)dir * NBKT + bkt) * SLACK;
    const int cnt = min(gcnt[dir * 256 + bkt], SLACK);
    const int cbase = csr_base[dir * 200 + bkt];
    const int n0 = bkt * 512;

    __shared__ int deg[512];
    __shared__ int sA[512], sB[512];
    __shared__ int cur[512];
    deg[t] = 0; deg[t + 256] = 0;
    __syncthreads();
    for (int i = t; i < cnt; i += 256)
        atomicAdd(&deg[recs[i] & 511u], 1);
    __syncthreads();
    sA[t] = deg[t]; sA[t + 256] = deg[t + 256];
    __syncthreads();
    int* pa = sA; int* pb = sB;
    for (int d = 1; d < 512; d <<= 1) {
        pb[t]       = pa[t]       + (t >= d           ? pa[t - d]       : 0);
        pb[t + 256] = pa[t + 256] + ((t + 256) >= d   ? pa[t + 256 - d] : 0);
        __syncthreads();
        int* tmp = pa; pa = pb; pb = tmp;
    }
    #pragma unroll
    for (int k = 0; k < 2; ++k) {
        int i = t + k * 256;
        int off = pa[i] - deg[i];          // exclusive
        cur[i] = off;
        int node = n0 + i;
        if (node < NN) {
            rp[node] = cbase + off;        // coalesced rp write
            inv[node] = 1.0f / (float)max(deg[i], 1);
        }
    }
    if (bkt == NBKT - 1 && t == 0) rp[NN] = csr_base[dir * 200 + NBKT];
    __syncthreads();
    for (int i = t; i < cnt; i += 256) {
        unsigned r = recs[i];
        int p = atomicAdd(&cur[r & 511u], 1);
        csr[cbase + p] = (int)(r >> 9);    // scattered 4B stores within ~10KB window
    }
}

// ---------------- mean aggregation (bf16, fused both directions, unroll-4) ----------------
__global__ void aggregate2_kernel(
    const unsigned short* __restrict__ h0, const int* __restrict__ rp0,
    const int* __restrict__ csr0, const float* __restrict__ inv0, unsigned short* __restrict__ ag0,
    const unsigned short* __restrict__ h1, const int* __restrict__ rp1,
    const int* __restrict__ csr1, const float* __restrict__ inv1, unsigned short* __restrict__ ag1)
{
    const int dir = blockIdx.y;
    const unsigned short* __restrict__ h = dir ? h1 : h0;
    const int* __restrict__ rp   = dir ? rp1 : rp0;
    const int* __restrict__ csr  = dir ? csr1 : csr0;
    const float* __restrict__ inv = dir ? inv1 : inv0;
    unsigned short* __restrict__ agg = dir ? ag1 : ag0;

    int wid  = (int)((blockIdx.x * 256u + threadIdx.x) >> 6);
    int lane = threadIdx.x & 63;
    if (wid >= NN) return;
    int beg = rp[wid], end = rp[wid + 1];
    float s0 = 0.f, s1 = 0.f, t0 = 0.f, t1 = 0.f;
    float u0 = 0.f, u1 = 0.f, v0 = 0.f, v1 = 0.f;
    int i = beg;
    for (; i + 3 < end; i += 4) {          // unroll-4: four independent gather chains
        int c0 = csr[i], c1 = csr[i + 1], c2 = csr[i + 2], c3 = csr[i + 3];
        unsigned w0 = *(const unsigned*)(h + (size_t)c0 * DD + lane * 2);
        unsigned w1 = *(const unsigned*)(h + (size_t)c1 * DD + lane * 2);
        unsigned w2 = *(const unsigned*)(h + (size_t)c2 * DD + lane * 2);
        unsigned w3 = *(const unsigned*)(h + (size_t)c3 * DD + lane * 2);
        s0 += __uint_as_float(w0 << 16); s1 += __uint_as_float(w0 & 0xffff0000u);
        t0 += __uint_as_float(w1 << 16); t1 += __uint_as_float(w1 & 0xffff0000u);
        u0 += __uint_as_float(w2 << 16); u1 += __uint_as_float(w2 & 0xffff0000u);
        v0 += __uint_as_float(w3 << 16); v1 += __uint_as_float(w3 & 0xffff0000u);
    }
    for (; i < end; ++i) {
        unsigned w = *(const unsigned*)(h + (size_t)csr[i] * DD + lane * 2);
        s0 += __uint_as_float(w << 16); s1 += __uint_as_float(w & 0xffff0000u);
    }
    float sc = inv[wid];
    float a0 = ((s0 + t0) + (u0 + v0)) * sc;
    float a1 = ((s1 + t1) + (u1 + v1)) * sc;
    unsigned o = (unsigned)f2bf(a0) | ((unsigned)f2bf(a1) << 16);
    *(unsigned*)(agg + (size_t)wid * DD + lane * 2) = o;
}

// ---------------- MFMA GEMM (fused both directions), high-occupancy ----------------
// out = relu([Hself|Hagg] @ [Wself|Wneigh]^T + b), bf16 in, fp32 acc.
// 512-thread block = 8 waves: M=256 rows x N=128 cols; each wave one 64x64 tile
// (4x4 MFMA 16x16x32), fused K=256. Weights staged once in LDS (64 KB, swizzled).
// A-fragments: global->VGPR direct, 1-deep register prefetch, SGPR-base+voffset
// addressing. 2 barriers/block (post-weight-stage, pre-epilogue).
// __launch_bounds__(512,4): VGPR<=128 -> 2 blocks/CU = 16 waves/CU (vs 8 in R3/R4).
// In-place safe: block owns its 256 rows; pre-epilogue barrier orders all A-reads
// before any store (no timing assumption).
__global__ __launch_bounds__(512, 4) void mfma_gemm5_kernel(
    const unsigned short* __restrict__ Hs0, const unsigned short* __restrict__ Ha0,
    const unsigned short* __restrict__ Ws0, const unsigned short* __restrict__ Wn0,
    const float* __restrict__ bias0, float* __restrict__ outF0, unsigned short* __restrict__ outB0,
    const unsigned short* __restrict__ Hs1, const unsigned short* __restrict__ Ha1,
    const unsigned short* __restrict__ Ws1, const unsigned short* __restrict__ Wn1,
    const float* __restrict__ bias1, float* __restrict__ outF1, unsigned short* __restrict__ outB1,
    int M)
{
    const int dir = blockIdx.y;
    const unsigned short* __restrict__ Hself = dir ? Hs1 : Hs0;
    const unsigned short* __restrict__ Hagg  = dir ? Ha1 : Ha0;
    const unsigned short* __restrict__ Wself = dir ? Ws1 : Ws0;
    const unsigned short* __restrict__ Wneigh= dir ? Wn1 : Wn0;
    const float* __restrict__ bias = dir ? bias1 : bias0;
    float* __restrict__ outF = dir ? outF1 : outF0;
    unsigned short* __restrict__ outB = dir ? outB1 : outB0;

    __shared__ __align__(16) unsigned short sW[128 * 256];  // fused weights, swizzled (64 KB)
    const int tid  = threadIdx.x;
    const int lane = tid & 63;
    const int w    = tid >> 6;                // 0..7
    const int row0 = blockIdx.x * 256;

    #pragma unroll
    for (int i = 0; i < 8; ++i) {             // stage fused weights (swizzled): 128B/thread
        int q = i * 512 + tid;                // 0..4095
        int n = q >> 5, c = q & 31;
        const unsigned short* src = (c < 16) ? (Wself + n * 128 + c * 8)
                                             : (Wneigh + n * 128 + (c - 16) * 8);
        int d = n * 256 + (c & 24) * 8 + (((c ^ n) & 7) * 8);
        *(uint4*)(sW + d) = *(const uint4*)src;
    }

    f32x4 acc[4][4];
    #pragma unroll
    for (int mt = 0; mt < 4; ++mt)
        #pragma unroll
        for (int nt = 0; nt < 4; ++nt) acc[mt][nt] = (f32x4){0.f, 0.f, 0.f, 0.f};

    const int mbase = (w >> 1) * 64;          // 0,64,128,192
    const int nbase = (w & 1) * 64;           // 0,64
    const int l15 = lane & 15;
    const int l4  = lane >> 4;

    // A-row offsets in shorts (clamped); SGPR base + 32-bit voffset addressing
    int voff[4];
    #pragma unroll
    for (int mt = 0; mt < 4; ++mt) {
        int grow = row0 + mbase + mt * 16 + l15;
        if (grow >= M) grow = M - 1;
        voff[mt] = grow * 128 + l4 * 8;
    }

    __syncthreads();   // weights ready

    bf16x8 a_cur[4], a_nxt[4];
    #pragma unroll
    for (int mt = 0; mt < 4; ++mt) a_cur[mt] = *(const bf16x8*)(Hself + voff[mt]);

    #pragma unroll
    for (int ks = 0; ks < 8; ++ks) {
        if (ks < 7) {
            const int ks1 = ks + 1;
            const int col = (ks1 & 3) * 32;     // shorts
            const unsigned short* __restrict__ base = (ks1 < 4) ? Hself : Hagg;  // compile-time per unrolled iter
            #pragma unroll
            for (int mt = 0; mt < 4; ++mt)
                a_nxt[mt] = *(const bf16x8*)(base + voff[mt] + col);
        }
        const int c = ks * 4 + l4;
        #pragma unroll
        for (int mt = 0; mt < 4; ++mt) {
            // B just-in-time from LDS (latency hidden under MFMA stream)
            int n0 = nbase + 0 * 16 + l15;
            int n1 = nbase + 1 * 16 + l15;
            int n2 = nbase + 2 * 16 + l15;
            int n3 = nbase + 3 * 16 + l15;
            bf16x8 b0 = *(const bf16x8*)(sW + n0 * 256 + (c & 24) * 8 + (((c ^ n0) & 7) * 8));
            bf16x8 b1 = *(const bf16x8*)(sW + n1 * 256 + (c & 24) * 8 + (((c ^ n1) & 7) * 8));
            bf16x8 b2 = *(const bf16x8*)(sW + n2 * 256 + (c & 24) * 8 + (((c ^ n2) & 7) * 8));
            bf16x8 b3 = *(const bf16x8*)(sW + n3 * 256 + (c & 24) * 8 + (((c ^ n3) & 7) * 8));
            acc[mt][0] = __builtin_amdgcn_mfma_f32_16x16x32_bf16(a_cur[mt], b0, acc[mt][0], 0, 0, 0);
            acc[mt][1] = __builtin_amdgcn_mfma_f32_16x16x32_bf16(a_cur[mt], b1, acc[mt][1], 0, 0, 0);
            acc[mt][2] = __builtin_amdgcn_mfma_f32_16x16x32_bf16(a_cur[mt], b2, acc[mt][2], 0, 0, 0);
            acc[mt][3] = __builtin_amdgcn_mfma_f32_16x16x32_bf16(a_cur[mt], b3, acc[mt][3], 0, 0, 0);
        }
        #pragma unroll
        for (int mt = 0; mt < 4; ++mt) a_cur[mt] = a_nxt[mt];
    }

    __syncthreads();   // all A-reads done before any in-place store (no timing assumption)

    #pragma unroll
    for (int nt = 0; nt < 4; ++nt) {
        int col = nbase + nt * 16 + l15;
        float bj = bias[col];
        #pragma unroll
        for (int mt = 0; mt < 4; ++mt) {
            #pragma unroll
            for (int r = 0; r < 4; ++r) {
                int grow = row0 + mbase + mt * 16 + l4 * 4 + r;
                if (grow < M) {
                    float v = fmaxf(acc[mt][nt][r] + bj, 0.f);
                    if (outF) outF[(size_t)grow * 128 + col] = v;
                    else      outB[(size_t)grow * 128 + col] = f2bf(v);
                }
            }
        }
    }
}

extern "C" void kernel_launch(void* const* d_in, const int* in_sizes, int n_in,
                              void* d_out, int out_size, void* d_ws, size_t ws_size,
                              hipStream_t stream) {
    const float* x_src        = (const float*)d_in[0];
    const float* x_dst        = (const float*)d_in[1];
    const int*   e_src        = (const int*)d_in[2];
    const int*   e_dst        = (const int*)d_in[3];
    const float* W_ship_self  = (const float*)d_in[4];
    const float* W_ship_neigh = (const float*)d_in[5];
    const float* b_ship       = (const float*)d_in[6];
    const float* W_rev_self   = (const float*)d_in[7];
    const float* W_rev_neigh  = (const float*)d_in[8];
    const float* b_rev        = (const float*)d_in[9];
    float* out = (float*)d_out;

    char* ws = (char*)d_ws;
    size_t off = 0;
    auto alloc = [&](size_t bytes) {
        char* p = ws + off;
        off = (off + bytes + 255) & ~(size_t)255;
        return p;
    };
    unsigned short* xs_bf = (unsigned short*)alloc((size_t)NN * DD * 2);
    unsigned short* xd_bf = (unsigned short*)alloc((size_t)NN * DD * 2);
    unsigned short* agg1  = (unsigned short*)alloc((size_t)NN * DD * 2);
    unsigned short* agg2  = (unsigned short*)alloc((size_t)NN * DD * 2);
    unsigned short* Wss_bf = (unsigned short*)alloc(2 * DD * DD * 2);
    unsigned short* Wsn_bf = (unsigned short*)alloc(2 * DD * DD * 2);
    unsigned short* Wrs_bf = (unsigned short*)alloc(2 * DD * DD * 2);
    unsigned short* Wrn_bf = (unsigned short*)alloc(2 * DD * DD * 2);
    int* gcnt = (int*)alloc(2 * 256 * 4);
    int* csr_base = (int*)alloc(2 * 200 * 4);
    unsigned* recbin = (unsigned*)alloc((size_t)2 * NBKT * SLACK * 4);
    int* rp_dst = (int*)alloc((NN + 1) * 4);
    int* rp_src = (int*)alloc((NN + 1) * 4);
    float* inv_dst = (float*)alloc(NN * 4);
    float* inv_src = (float*)alloc(NN * 4);
    int* csr_dst = (int*)alloc(EDGES * 4);
    int* csr_src = (int*)alloc(EDGES * 4);
    (void)ws_size; (void)in_sizes; (void)n_in; (void)out_size;

    hipMemsetAsync(gcnt, 0, 2 * 256 * 4, stream);

    const int xn4 = NN * DD / 4;                       // 3,200,000
    f2bx_kernel<<<dim3(xn4 / 256, 2), 256, 0, stream>>>(x_src, x_dst, xs_bf, xd_bf);
    f2bw_kernel<<<dim3(32, 4), 256, 0, stream>>>(W_ship_self, W_ship_neigh, W_rev_self, W_rev_neigh,
                                                 Wss_bf, Wsn_bf, Wrs_bf, Wrn_bf);

    bin_scatter_kernel<<<dim3(BPD, 2), 256, 0, stream>>>(e_src, e_dst, gcnt, recbin);
    bucket_scan_kernel<<<1, 256, 0, stream>>>(gcnt, csr_base);
    fine_place_kernel<<<dim3(NBKT, 2), 256, 0, stream>>>(recbin, gcnt, csr_base,
        rp_dst, rp_src, inv_dst, inv_src, csr_dst, csr_src);

    float* out_s = out;                       // h_s final
    float* out_d = out + (size_t)NN * DD;     // h_d final
    const int gemm_grid = (NN + 255) / 256;   // 391 (M=256 per block)
    const int agg_grid  = (NN * 64 + 255) / 256;  // 25000

    for (int l = 0; l < 2; ++l) {
        // dir0: agg1 = mean h_s by dst ; dir1: agg2 = mean h_d by src
        aggregate2_kernel<<<dim3(agg_grid, 2), 256, 0, stream>>>(
            xs_bf, rp_dst, csr_dst, inv_dst, agg1,
            xd_bf, rp_src, csr_src, inv_src, agg2);
        // dir0: new_d = relu(h_d@Wss^T + agg1@Wsn^T + b_ship)
        // dir1: new_s = relu(h_s@Wrs^T + agg2@Wrn^T + b_rev)
        mfma_gemm5_kernel<<<dim3(gemm_grid, 2), 512, 0, stream>>>(
            xd_bf, agg1, Wss_bf + l * DD * DD, Wsn_bf + l * DD * DD, b_ship + l * DD,
            l ? out_d : nullptr, l ? nullptr : xd_bf,
            xs_bf, agg2, Wrs_bf + l * DD * DD, Wrn_bf + l * DD * DD, b_rev + l * DD,
            l ? out_s : nullptr, l ? nullptr : xs_bf,
            NN);
    }
}